// Round 7
// baseline (199.349 us; speedup 1.0000x reference)
//
#include <hip/hip_runtime.h>
#include <hip/hip_bf16.h>

// SparseLinear forward exploiting ~50% zero rows of x:
//   1) prep: blocks [0,4096): per-row zero detect -> compacted bf16 A + rowmap,
//            zero rows get y[row]=bias directly. blocks [4096,6144): W -> bf16.
//   2) gemm_cmp: persistent 512 blocks (exactly 2/CU), atomic tile queue over
//      nact = ceil(Mc/128)*32 tiles of 128x128; BK=64 dbuf pipeline with
//      counted vmcnt(4), zero-conflict XOR swizzle, setprio MFMA, scatter
//      epilogue through rowmap. Inner loop identical to R6 (verified).

typedef __bf16 bf16x8 __attribute__((ext_vector_type(8)));
typedef float f32x4 __attribute__((ext_vector_type(4)));

constexpr int Mfull = 4096;  // T*B
constexpr int Nn = 4096;     // C_OUT
constexpr int Kk = 4096;     // C_IN
constexpr int GBM = 128, GBN = 128, GBK = 64;
constexpr int GNT = Kk / GBK;          // 64 K-tiles
// dbuf = 16384 elems (32 KiB): [A_k0][A_k1][B_k0][B_k1], each [128 rows][32 k]
constexpr int GDBUF = 16384;
constexpr int GA0 = 0, GA1 = 4096, GB0 = 8192, GB1 = 12288;
constexpr int GEMM_BLOCKS = 512;       // exactly 2 per CU

__device__ int g_Mc;
__device__ int g_q;
__device__ int g_rowmap[Mfull];

__device__ __forceinline__ unsigned short f2bf_rne(float f) {
    unsigned int u = __float_as_uint(f);
    u += 0x7fffu + ((u >> 16) & 1u);   // round-to-nearest-even
    return (unsigned short)(u >> 16);
}

__global__ void reset_counters() {
    if (threadIdx.x == 0) { g_Mc = 0; g_q = 0; }
}

// Fused prep. Blocks [0, Mfull): compact/convert one x-row (or bias-fill out).
// Blocks [Mfull, Mfull+2048): grid-stride convert W fp32 -> bf16.
__global__ __launch_bounds__(256) void prep(
    const float* __restrict__ x, const float* __restrict__ w,
    const float* __restrict__ bias,
    unsigned short* __restrict__ Abf, unsigned short* __restrict__ Bbf,
    float* __restrict__ out)
{
    const int tid = threadIdx.x;
    if (blockIdx.x < Mfull) {
        const int row = blockIdx.x;
        const float4* xr = (const float4*)(x + (size_t)row * Kk);
        float4 v[4];
        bool nz = false;
#pragma unroll
        for (int i = 0; i < 4; ++i) {
            v[i] = xr[i * 256 + tid];
            nz = nz | (v[i].x != 0.f) | (v[i].y != 0.f) |
                      (v[i].z != 0.f) | (v[i].w != 0.f);
        }
        __shared__ int s_flag, s_pos;
        if (tid == 0) s_flag = 0;
        __syncthreads();
        if (nz) s_flag = 1;
        __syncthreads();
        if (tid == 0 && s_flag) {
            const int p = atomicAdd(&g_Mc, 1);
            g_rowmap[p] = row;
            s_pos = p;
        }
        __syncthreads();
        if (s_flag) {
            unsigned short* dst = Abf + (size_t)s_pos * Kk;
#pragma unroll
            for (int i = 0; i < 4; ++i) {
                ushort4 r;
                r.x = f2bf_rne(v[i].x); r.y = f2bf_rne(v[i].y);
                r.z = f2bf_rne(v[i].z); r.w = f2bf_rne(v[i].w);
                *(ushort4*)(dst + i * 1024 + tid * 4) = r;
            }
        } else {
            const float4* bv = (const float4*)bias;
            float4* orow = (float4*)(out + (size_t)row * Nn);
#pragma unroll
            for (int i = 0; i < 4; ++i) orow[i * 256 + tid] = bv[i * 256 + tid];
        }
    } else {
        const int b = blockIdx.x - Mfull;          // 0..2047
        const int n8 = (Nn * Kk) / 8;
        const int stride = 2048 * 256;
        for (int i = b * 256 + tid; i < n8; i += stride) {
            long base = (long)i * 8;
            float4 v0 = *(const float4*)(w + base);
            float4 v1 = *(const float4*)(w + base + 4);
            ushort4 r0, r1;
            r0.x = f2bf_rne(v0.x); r0.y = f2bf_rne(v0.y);
            r0.z = f2bf_rne(v0.z); r0.w = f2bf_rne(v0.w);
            r1.x = f2bf_rne(v1.x); r1.y = f2bf_rne(v1.y);
            r1.z = f2bf_rne(v1.z); r1.w = f2bf_rne(v1.w);
            *(ushort4*)(Bbf + base) = r0;
            *(ushort4*)(Bbf + base + 4) = r1;
        }
    }
}

// Stage one [128 rows][32 k] unit (8 KiB) via 2 global_load_lds per thread.
// Linear LDS dest; pre-swizzled global source: cg ^= (row>>1)&3.
__device__ __forceinline__ void stage_u128(const unsigned short* __restrict__ g,
                                           size_t grow0, int kcol0,
                                           unsigned short* unitbase,
                                           int tid, int wave) {
#pragma unroll
    for (int i = 0; i < 2; ++i) {
        const int row = i * 64 + (tid >> 2);
        const int cg  = (tid & 3) ^ ((row >> 1) & 3);
        const unsigned short* src = g + (grow0 + (size_t)row) * (size_t)Kk
                                      + (size_t)(kcol0 + cg * 8);
        unsigned short* dst = unitbase + i * 2048 + wave * 512;
        __builtin_amdgcn_global_load_lds(
            (const __attribute__((address_space(1))) void*)src,
            (__attribute__((address_space(3))) void*)dst, 16, 0, 0);
    }
}

__global__ __launch_bounds__(256, 2) void gemm_cmp(
    const unsigned short* __restrict__ A,   // [Mc][K] compacted bf16
    const unsigned short* __restrict__ B,   // [N][K] bf16
    const float* __restrict__ bias,         // [N]
    float* __restrict__ C)                  // [Mfull][N] fp32 (scatter target)
{
    __shared__ unsigned short lds[2 * GDBUF];   // 64 KiB -> 2 blocks/CU
    __shared__ int s_t;

    const int Mc = *(volatile int*)&g_Mc;
    const int nbm  = (Mc + GBM - 1) / GBM;      // active bm rows
    const int nact = nbm * (Nn / GBN);          // active tiles

    const int tid  = threadIdx.x;
    const int wave = tid >> 6;
    const int lane = tid & 63;
    const int wr = wave >> 1;       // 0..1 (64 rows each)
    const int wc = wave & 1;        // 0..1 (64 cols each)
    const int lr = lane & 15;
    const int kg = lane >> 4;

    const int a_row0 = wr * 64 + lr;
    const int b_row0 = wc * 64 + lr;
    const int aoff = a_row0 * 32 + ((kg ^ ((a_row0 >> 1) & 3)) << 3);
    const int boff = b_row0 * 32 + ((kg ^ ((b_row0 >> 1) & 3)) << 3);

    for (;;) {
        // ---- pull next tile ticket (uniform across block) ----
        if (tid == 0) s_t = atomicAdd(&g_q, 1);
        __syncthreads();
        const int ti = s_t;
        if (ti >= nact) return;

        const int bm = ti >> 5, bn = ti & 31;   // nact = nbm*32, row-major
        const size_t brow = (size_t)bm * GBM;
        const size_t bcol = (size_t)bn * GBN;

        f32x4 acc[4][4];
#pragma unroll
        for (int m = 0; m < 4; ++m)
#pragma unroll
            for (int n = 0; n < 4; ++n)
                acc[m][n] = (f32x4){0.f, 0.f, 0.f, 0.f};

        // ---- prologue: stage tile 0's 4 units (8 loads) ----
        stage_u128(A, brow, 0,  lds + GA0, tid, wave);
        stage_u128(B, bcol, 0,  lds + GB0, tid, wave);
        stage_u128(A, brow, 32, lds + GA1, tid, wave);
        stage_u128(B, bcol, 32, lds + GB1, tid, wave);
        asm volatile("s_waitcnt vmcnt(4)" ::: "memory");   // A_k0,B_k0 landed
        __builtin_amdgcn_s_barrier();

        for (int t = 0; t < GNT; ++t) {
            unsigned short* db = lds + (t & 1) * GDBUF;
            unsigned short* pb = lds + ((t & 1) ^ 1) * GDBUF;
            const int ktn = (t + 1) * GBK;
            const bool pf = (t + 1) < GNT;

            bf16x8 a[4], b[4];

            // ===== phase k0 =====
#pragma unroll
            for (int n = 0; n < 4; ++n) b[n] = *(const bf16x8*)(db + GB0 + boff + n * 512);
#pragma unroll
            for (int m = 0; m < 4; ++m) a[m] = *(const bf16x8*)(db + GA0 + aoff + m * 512);
            if (pf) {
                stage_u128(A, brow, ktn, pb + GA0, tid, wave);
                stage_u128(B, bcol, ktn, pb + GB0, tid, wave);
            }
            __builtin_amdgcn_s_barrier();
            asm volatile("s_waitcnt lgkmcnt(0)" ::: "memory");
            __builtin_amdgcn_sched_barrier(0);
            __builtin_amdgcn_s_setprio(1);
#pragma unroll
            for (int m = 0; m < 4; ++m)
#pragma unroll
                for (int n = 0; n < 4; ++n)
                    acc[m][n] = __builtin_amdgcn_mfma_f32_16x16x32_bf16(
                        a[m], b[n], acc[m][n], 0, 0, 0);
            __builtin_amdgcn_s_setprio(0);
            // drain A_k1,B_k1(t) (oldest 4); keep A_k0,B_k0(t+1) in flight
            if (pf) { asm volatile("s_waitcnt vmcnt(4)" ::: "memory"); }
            else    { asm volatile("s_waitcnt vmcnt(0)" ::: "memory"); }
            __builtin_amdgcn_s_barrier();

            // ===== phase k1 =====
#pragma unroll
            for (int n = 0; n < 4; ++n) b[n] = *(const bf16x8*)(db + GB1 + boff + n * 512);
#pragma unroll
            for (int m = 0; m < 4; ++m) a[m] = *(const bf16x8*)(db + GA1 + aoff + m * 512);
            if (pf) {
                stage_u128(A, brow, ktn + 32, pb + GA1, tid, wave);
                stage_u128(B, bcol, ktn + 32, pb + GB1, tid, wave);
            }
            __builtin_amdgcn_s_barrier();
            asm volatile("s_waitcnt lgkmcnt(0)" ::: "memory");
            __builtin_amdgcn_sched_barrier(0);
            __builtin_amdgcn_s_setprio(1);
#pragma unroll
            for (int m = 0; m < 4; ++m)
#pragma unroll
                for (int n = 0; n < 4; ++n)
                    acc[m][n] = __builtin_amdgcn_mfma_f32_16x16x32_bf16(
                        a[m], b[n], acc[m][n], 0, 0, 0);
            __builtin_amdgcn_s_setprio(0);
            // drain A_k0,B_k0(t+1); keep A_k1,B_k1(t+1) in flight
            if (pf) {
                asm volatile("s_waitcnt vmcnt(4)" ::: "memory");
                __builtin_amdgcn_s_barrier();
            }
        }

        // ---- epilogue: scatter via rowmap, mask rows >= Mc; fused bias ----
        float bsv[4];
#pragma unroll
        for (int n = 0; n < 4; ++n) bsv[n] = bias[bcol + wc * 64 + n * 16 + lr];
        const int rbase = bm * GBM + wr * 64 + kg * 4;
#pragma unroll
        for (int m = 0; m < 4; ++m) {
            const int r0 = rbase + m * 16;
#pragma unroll
            for (int j = 0; j < 4; ++j) {
                const int rr = r0 + j;
                if (rr < Mc) {
                    const size_t orow = (size_t)g_rowmap[rr] * (size_t)Nn;
#pragma unroll
                    for (int n = 0; n < 4; ++n) {
                        C[orow + bcol + wc * 64 + n * 16 + lr] = acc[m][n][j] + bsv[n];
                    }
                }
            }
        }
        __syncthreads();   // LDS + s_t safe for next ticket
    }
}

extern "C" void kernel_launch(void* const* d_in, const int* in_sizes, int n_in,
                              void* d_out, int out_size, void* d_ws, size_t ws_size,
                              hipStream_t stream) {
    const float* x    = (const float*)d_in[0];   // [T,B,C_IN] = [M,K]
    const float* w    = (const float*)d_in[1];   // [C_OUT,C_IN] = [N,K]
    const float* bias = (const float*)d_in[2];   // [N]
    float* out = (float*)d_out;                  // [M,N]

    unsigned short* Abf = (unsigned short*)d_ws;           // 32 MiB (compacted)
    unsigned short* Bbf = Abf + (size_t)Mfull * Kk;        // 32 MiB

    reset_counters<<<1, 64, 0, stream>>>();
    prep<<<Mfull + 2048, 256, 0, stream>>>(x, w, bias, Abf, Bbf, out);
    gemm_cmp<<<GEMM_BLOCKS, 256, 0, stream>>>(Abf, Bbf, bias, out);
}

// Round 8
// 168.204 us; speedup vs baseline: 1.1852x; 1.1852x over previous
//
#include <hip/hip_runtime.h>
#include <hip/hip_bf16.h>

// SparseLinear forward as DENSE bf16 MFMA GEMM (sparsity path reverted — R5-R7
// showed its FLOP savings are eaten by tile-geometry/occupancy losses).
//   C[M,N] = A[M,K] * B[N,K]^T + bias,  M=N=K=4096.
// R8 change vs R4: MFMA shape 16x16x32 -> 32x32x16 (4x FLOP/instruction,
// half the instruction count per phase). Skeleton identical to verified R3/R4:
// 256x256 tile, BK=64 as two [256][32] k-units, 8 waves (2Mx4N, wave tile
// 128x64), 2 phases/K-tile, counted vmcnt(4) ledger, granule-XOR swizzle,
// setprio around MFMA clusters, fused-bias epilogue.

typedef __bf16 bf16x8 __attribute__((ext_vector_type(8)));
typedef float f32x16 __attribute__((ext_vector_type(16)));

constexpr int M = 4096;   // T*B
constexpr int N = 4096;   // C_OUT
constexpr int K = 4096;   // C_IN
constexpr int BM = 256, BN = 256, BK = 64;
constexpr int NT = K / BK;          // 64 K-tiles
// One dbuf = 32768 elems (64 KiB): [A_k0][A_k1][B_k0][B_k1], each [256][32]
constexpr int DBUF = 32768;
constexpr int A_K0 = 0, A_K1 = 8192, B_K0 = 16384, B_K1 = 24576;

__device__ __forceinline__ unsigned short f2bf_rne(float f) {
    unsigned int u = __float_as_uint(f);
    u += 0x7fffu + ((u >> 16) & 1u);   // round-to-nearest-even
    return (unsigned short)(u >> 16);
}

__global__ __launch_bounds__(256) void cvt_f32_bf16(const float* __restrict__ in,
                                                    unsigned short* __restrict__ out,
                                                    int n8) {
    int idx = blockIdx.x * blockDim.x + threadIdx.x;
    int stride = gridDim.x * blockDim.x;
    for (int i = idx; i < n8; i += stride) {
        long base = (long)i * 8;
        float4 v0 = *(const float4*)(in + base);
        float4 v1 = *(const float4*)(in + base + 4);
        ushort4 r0, r1;
        r0.x = f2bf_rne(v0.x); r0.y = f2bf_rne(v0.y);
        r0.z = f2bf_rne(v0.z); r0.w = f2bf_rne(v0.w);
        r1.x = f2bf_rne(v1.x); r1.y = f2bf_rne(v1.y);
        r1.z = f2bf_rne(v1.z); r1.w = f2bf_rne(v1.w);
        *(ushort4*)(out + base) = r0;
        *(ushort4*)(out + base + 4) = r1;
    }
}

// Stage one k-half unit ([256 rows][32 k] = 16 KiB, 2 global_load_lds) into
// LDS (linear dest, pre-swizzled global source: granule ^= (row>>1)&3).
__device__ __forceinline__ void stage_unit(const unsigned short* __restrict__ g,
                                           size_t grow0, int kcol0,
                                           unsigned short* unitbase,
                                           int tid, int wave) {
#pragma unroll
    for (int i = 0; i < 2; ++i) {
        const int row = i * 128 + (tid >> 2);
        const int cg  = (tid & 3) ^ ((row >> 1) & 3);
        const unsigned short* src = g + (grow0 + (size_t)row) * (size_t)K
                                      + (size_t)(kcol0 + cg * 8);
        unsigned short* dst = unitbase + i * 4096 + wave * 512;
        __builtin_amdgcn_global_load_lds(
            (const __attribute__((address_space(1))) void*)src,
            (__attribute__((address_space(3))) void*)dst, 16, 0, 0);
    }
}

__global__ __launch_bounds__(512, 2) void gemm_3232(
    const unsigned short* __restrict__ A,   // [M][K] bf16 bits
    const unsigned short* __restrict__ B,   // [N][K] bf16 bits
    const float* __restrict__ bias,         // [N]
    float* __restrict__ C)                  // [M][N] fp32
{
    __shared__ unsigned short lds[2 * DBUF];   // 128 KiB

    // XCD-aware bijective swizzle: 256 wgs, 256 % 8 == 0
    const int wg = blockIdx.x;
    const int sw = ((wg & 7) << 5) | (wg >> 3);
    const int bm = sw >> 4, bn = sw & 15;
    const size_t brow = (size_t)bm * BM;
    const size_t bcol = (size_t)bn * BN;

    const int tid  = threadIdx.x;
    const int wave = tid >> 6;
    const int lane = tid & 63;
    const int wr = wave >> 2;       // 0..1  (2 M-waves, 128 rows each)
    const int wc = wave & 3;        // 0..3  (4 N-waves, 64 cols each)
    const int l31 = lane & 31;      // 32x32 fragment row
    const int hi  = lane >> 5;      // k-half within fragment

    // Per-lane swizzled element offsets within a [256][32] unit.
    // Fragment element: row = base + mi*32 + l31, k = s*16 + hi*8 + j.
    // Stored granule = (s*2+hi) ^ ((row>>1)&3); mi*32 rows don't change XOR.
    const int arow = wr * 128 + l31;
    const int brw  = wc * 64 + l31;
    const int swa = (arow >> 1) & 3;
    const int swb = (brw >> 1) & 3;
    const int aoff0 = arow * 32 + (((0 + hi) ^ swa) << 3);   // s=0
    const int aoff1 = arow * 32 + (((2 + hi) ^ swa) << 3);   // s=1
    const int boff0 = brw * 32 + (((0 + hi) ^ swb) << 3);
    const int boff1 = brw * 32 + (((2 + hi) ^ swb) << 3);

    f32x16 acc[4][2];
#pragma unroll
    for (int mi = 0; mi < 4; ++mi)
#pragma unroll
        for (int ni = 0; ni < 2; ++ni)
#pragma unroll
            for (int r = 0; r < 16; ++r)
                acc[mi][ni][r] = 0.f;

    // ---- prologue: stage tile 0's 4 units (8 loads) ----
    stage_unit(A, brow, 0,  lds + A_K0, tid, wave);
    stage_unit(B, bcol, 0,  lds + B_K0, tid, wave);
    stage_unit(A, brow, 32, lds + A_K1, tid, wave);
    stage_unit(B, bcol, 32, lds + B_K1, tid, wave);
    asm volatile("s_waitcnt vmcnt(4)" ::: "memory");   // A_k0, B_k0 landed
    __builtin_amdgcn_s_barrier();

    for (int t = 0; t < NT; ++t) {
        unsigned short* db = lds + (t & 1) * DBUF;        // compute buffer
        unsigned short* pb = lds + ((t & 1) ^ 1) * DBUF;  // prefetch target
        const int ktn = (t + 1) * BK;
        const bool pf = (t + 1) < NT;

        bf16x8 af[4][2], bfr[2][2];

        // ===== P1: unit k0 (k = 0..31 of tile) =====
#pragma unroll
        for (int ni = 0; ni < 2; ++ni) {
            bfr[ni][0] = *(const bf16x8*)(db + B_K0 + boff0 + ni * 1024);
            bfr[ni][1] = *(const bf16x8*)(db + B_K0 + boff1 + ni * 1024);
        }
#pragma unroll
        for (int mi = 0; mi < 4; ++mi) {
            af[mi][0] = *(const bf16x8*)(db + A_K0 + aoff0 + mi * 1024);
            af[mi][1] = *(const bf16x8*)(db + A_K0 + aoff1 + mi * 1024);
        }
        if (pf) {
            stage_unit(A, brow, ktn, pb + A_K0, tid, wave);
            stage_unit(B, bcol, ktn, pb + B_K0, tid, wave);
        }
        __builtin_amdgcn_s_barrier();
        asm volatile("s_waitcnt lgkmcnt(0)" ::: "memory");
        __builtin_amdgcn_sched_barrier(0);
        __builtin_amdgcn_s_setprio(1);
#pragma unroll
        for (int s = 0; s < 2; ++s)
#pragma unroll
            for (int mi = 0; mi < 4; ++mi)
#pragma unroll
                for (int ni = 0; ni < 2; ++ni)
                    acc[mi][ni] = __builtin_amdgcn_mfma_f32_32x32x16_bf16(
                        af[mi][s], bfr[ni][s], acc[mi][ni], 0, 0, 0);
        __builtin_amdgcn_s_setprio(0);
        // drain A_k1,B_k1(t) (oldest 4); keep A_k0,B_k0(t+1) in flight
        if (pf) { asm volatile("s_waitcnt vmcnt(4)" ::: "memory"); }
        else    { asm volatile("s_waitcnt vmcnt(0)" ::: "memory"); }
        __builtin_amdgcn_s_barrier();

        // ===== P2: unit k1 (k = 32..63 of tile) =====
#pragma unroll
        for (int ni = 0; ni < 2; ++ni) {
            bfr[ni][0] = *(const bf16x8*)(db + B_K1 + boff0 + ni * 1024);
            bfr[ni][1] = *(const bf16x8*)(db + B_K1 + boff1 + ni * 1024);
        }
#pragma unroll
        for (int mi = 0; mi < 4; ++mi) {
            af[mi][0] = *(const bf16x8*)(db + A_K1 + aoff0 + mi * 1024);
            af[mi][1] = *(const bf16x8*)(db + A_K1 + aoff1 + mi * 1024);
        }
        if (pf) {
            stage_unit(A, brow, ktn + 32, pb + A_K1, tid, wave);
            stage_unit(B, bcol, ktn + 32, pb + B_K1, tid, wave);
        }
        __builtin_amdgcn_s_barrier();
        asm volatile("s_waitcnt lgkmcnt(0)" ::: "memory");
        __builtin_amdgcn_sched_barrier(0);
        __builtin_amdgcn_s_setprio(1);
#pragma unroll
        for (int s = 0; s < 2; ++s)
#pragma unroll
            for (int mi = 0; mi < 4; ++mi)
#pragma unroll
                for (int ni = 0; ni < 2; ++ni)
                    acc[mi][ni] = __builtin_amdgcn_mfma_f32_32x32x16_bf16(
                        af[mi][s], bfr[ni][s], acc[mi][ni], 0, 0, 0);
        __builtin_amdgcn_s_setprio(0);
        // drain A_k0,B_k0(t+1) (oldest 4); keep A_k1,B_k1(t+1) in flight
        if (pf) {
            asm volatile("s_waitcnt vmcnt(4)" ::: "memory");
            __builtin_amdgcn_s_barrier();
        }
    }

    // ---- epilogue: 32x32 C/D layout (m74/m101): col = lane&31,
    //      row = (reg&3) + 8*(reg>>2) + 4*(lane>>5); fused bias ----
    float bsv[2];
#pragma unroll
    for (int ni = 0; ni < 2; ++ni)
        bsv[ni] = bias[bcol + wc * 64 + ni * 32 + l31];
    const size_t row00 = brow + (size_t)wr * 128 + 4 * hi;
#pragma unroll
    for (int mi = 0; mi < 4; ++mi) {
#pragma unroll
        for (int ni = 0; ni < 2; ++ni) {
            const size_t col = bcol + wc * 64 + ni * 32 + l31;
#pragma unroll
            for (int r = 0; r < 16; ++r) {
                const size_t row = row00 + mi * 32 + (r & 3) + 8 * (r >> 2);
                C[row * N + col] = acc[mi][ni][r] + bsv[ni];
            }
        }
    }
}

extern "C" void kernel_launch(void* const* d_in, const int* in_sizes, int n_in,
                              void* d_out, int out_size, void* d_ws, size_t ws_size,
                              hipStream_t stream) {
    const float* x    = (const float*)d_in[0];   // [T,B,C_IN] = [M,K]
    const float* w    = (const float*)d_in[1];   // [C_OUT,C_IN] = [N,K]
    const float* bias = (const float*)d_in[2];   // [N]
    float* out = (float*)d_out;                  // [M,N]

    unsigned short* Abf = (unsigned short*)d_ws;           // 32 MiB
    unsigned short* Bbf = Abf + (size_t)M * K;             // 32 MiB

    const int n8 = (M * K) / 8;
    cvt_f32_bf16<<<2048, 256, 0, stream>>>(x, Abf, n8);
    cvt_f32_bf16<<<2048, 256, 0, stream>>>(w, Bbf, n8);

    gemm_3232<<<dim3((M / BM) * (N / BN)), 512, 0, stream>>>(Abf, Bbf, bias, out);
}

// Round 9
// 166.274 us; speedup vs baseline: 1.1989x; 1.0116x over previous
//
#include <hip/hip_runtime.h>
#include <hip/hip_bf16.h>

// SparseLinear forward as DENSE bf16 MFMA GEMM: C = A * B^T + bias (4096^3).
// R9: break the measured MFMA+LDS serialization (sum-model, R2-R4) via
// TWO co-resident blocks per CU (m114 overlap mechanism):
//   BM=256 x BN=128, BK=32, 4 waves (2x2, wave tile 128x64), 3-slot LDS ring
//   (72 KB -> exactly 2 blocks/CU), grid 512 = 2/CU (zero tail), strict
//   counted vmcnt(6) ledger with 2-tile staging lead, ONE barrier per K-tile,
//   verified zero-conflict granule-XOR swizzle, 16x16x32 MFMA (R8's 32x32
//   reverted: it added conflicts), fused-bias epilogue.

typedef __bf16 bf16x8 __attribute__((ext_vector_type(8)));
typedef float f32x4 __attribute__((ext_vector_type(4)));

constexpr int M = 4096;   // T*B
constexpr int N = 4096;   // C_OUT
constexpr int K = 4096;   // C_IN
constexpr int BM = 256, BN = 128, BK = 32;
constexpr int NT = K / BK;              // 128 K-tiles
constexpr int DB_A = BM * BK;           // 8192 elems
constexpr int DB_B = BN * BK;           // 4096 elems
constexpr int DBUF = DB_A + DB_B;       // 12288 elems = 24 KiB per ring slot

__device__ __forceinline__ unsigned short f2bf_rne(float f) {
    unsigned int u = __float_as_uint(f);
    u += 0x7fffu + ((u >> 16) & 1u);   // round-to-nearest-even
    return (unsigned short)(u >> 16);
}

// Fused convert: x -> Abf and w -> Bbf in one launch (both are [4096][4096]).
__global__ __launch_bounds__(256) void cvt_both(const float* __restrict__ x,
                                                const float* __restrict__ w,
                                                unsigned short* __restrict__ Abf,
                                                unsigned short* __restrict__ Bbf) {
    const int n8 = (M * K) / 8;             // chunks per array
    int idx = blockIdx.x * blockDim.x + threadIdx.x;
    int stride = gridDim.x * blockDim.x;
    for (int i = idx; i < 2 * n8; i += stride) {
        const float* src;
        unsigned short* dst;
        long base;
        if (i < n8) { base = (long)i * 8;        src = x + base; dst = Abf + base; }
        else        { base = (long)(i - n8) * 8; src = w + base; dst = Bbf + base; }
        float4 v0 = *(const float4*)(src);
        float4 v1 = *(const float4*)(src + 4);
        ushort4 r0, r1;
        r0.x = f2bf_rne(v0.x); r0.y = f2bf_rne(v0.y);
        r0.z = f2bf_rne(v0.z); r0.w = f2bf_rne(v0.w);
        r1.x = f2bf_rne(v1.x); r1.y = f2bf_rne(v1.y);
        r1.z = f2bf_rne(v1.z); r1.w = f2bf_rne(v1.w);
        *(ushort4*)(dst) = r0;
        *(ushort4*)(dst + 4) = r1;
    }
}

// Stage the A-unit ([256 rows][32 k], 16 KiB) : 4 global_load_lds per thread.
// Linear LDS dest; pre-swizzled global source granule: cg ^= (row>>1)&3.
__device__ __forceinline__ void stageA(const unsigned short* __restrict__ g,
                                       size_t grow0, int kcol0,
                                       unsigned short* base, int tid, int wave) {
#pragma unroll
    for (int j = 0; j < 4; ++j) {
        const int row = j * 64 + (tid >> 2);
        const int cg  = (tid & 3) ^ ((row >> 1) & 3);
        const unsigned short* src = g + (grow0 + (size_t)row) * (size_t)K
                                      + (size_t)(kcol0 + cg * 8);
        unsigned short* dst = base + j * 2048 + wave * 512;
        __builtin_amdgcn_global_load_lds(
            (const __attribute__((address_space(1))) void*)src,
            (__attribute__((address_space(3))) void*)dst, 16, 0, 0);
    }
}

// Stage the B-unit ([128 rows][32 k], 8 KiB): 2 global_load_lds per thread.
__device__ __forceinline__ void stageB(const unsigned short* __restrict__ g,
                                       size_t grow0, int kcol0,
                                       unsigned short* base, int tid, int wave) {
#pragma unroll
    for (int j = 0; j < 2; ++j) {
        const int row = j * 64 + (tid >> 2);
        const int cg  = (tid & 3) ^ ((row >> 1) & 3);
        const unsigned short* src = g + (grow0 + (size_t)row) * (size_t)K
                                      + (size_t)(kcol0 + cg * 8);
        unsigned short* dst = base + j * 2048 + wave * 512;
        __builtin_amdgcn_global_load_lds(
            (const __attribute__((address_space(1))) void*)src,
            (__attribute__((address_space(3))) void*)dst, 16, 0, 0);
    }
}

__global__ __launch_bounds__(256, 2) void gemm_2cu(
    const unsigned short* __restrict__ A,   // [M][K] bf16 bits
    const unsigned short* __restrict__ B,   // [N][K] bf16 bits
    const float* __restrict__ bias,         // [N]
    float* __restrict__ C)                  // [M][N] fp32
{
    __shared__ unsigned short lds[3 * DBUF];   // 72 KiB -> 2 blocks/CU

    // XCD-aware bijective swizzle: 512 wgs, 512 % 8 == 0.
    const int wg = blockIdx.x;
    const int s  = ((wg & 7) << 6) | (wg >> 3);
    const int bm = s >> 5, bn = s & 31;        // 16 x 32 tile grid
    const size_t brow = (size_t)bm * BM;
    const size_t bcol = (size_t)bn * BN;

    const int tid  = threadIdx.x;
    const int wave = tid >> 6;
    const int lane = tid & 63;
    const int wr = wave >> 1;       // 0..1 (128 rows each)
    const int wc = wave & 1;        // 0..1 (64 cols each)
    const int lr = lane & 15;
    const int kg = lane >> 4;

    const int arow0 = wr * 128 + lr;
    const int brw0  = wc * 64 + lr;
    const int aoff = arow0 * 32 + ((kg ^ ((arow0 >> 1) & 3)) << 3);
    const int boff = brw0  * 32 + ((kg ^ ((brw0  >> 1) & 3)) << 3);

    f32x4 acc[8][4];
#pragma unroll
    for (int m = 0; m < 8; ++m)
#pragma unroll
        for (int n = 0; n < 4; ++n)
            acc[m][n] = (f32x4){0.f, 0.f, 0.f, 0.f};

    // ---- prologue: stage tiles 0 (slot 0) and 1 (slot 1): 12 loads ----
    stageA(A, brow, 0,  lds,                tid, wave);
    stageB(B, bcol, 0,  lds + DB_A,         tid, wave);
    stageA(A, brow, BK, lds + DBUF,         tid, wave);
    stageB(B, bcol, BK, lds + DBUF + DB_A,  tid, wave);

    int cur = 0;
    for (int t = 0; t < NT; ++t) {
        // Entry wait: tile t (oldest 6 loads) landed; tile t+1's 6 stay in
        // flight. Strict ledger incl. tails (t=NT-1: nothing newer -> drain).
        if (t + 1 < NT) { asm volatile("s_waitcnt vmcnt(6)" ::: "memory"); }
        else            { asm volatile("s_waitcnt vmcnt(0)" ::: "memory"); }
        __builtin_amdgcn_s_barrier();
        __builtin_amdgcn_sched_barrier(0);

        unsigned short* ua = lds + cur * DBUF;
        unsigned short* ub = ua + DB_A;
        int nxt = cur + 2; if (nxt >= 3) nxt -= 3;   // ring slot for tile t+2
        const bool pf = (t + 2) < NT;
        const int ktn = (t + 2) * BK;

        bf16x8 a[8], b4[4];

        // ---- phase 1: B-frags + A m-half 0; stage A(t+2) ----
#pragma unroll
        for (int n = 0; n < 4; ++n) b4[n] = *(const bf16x8*)(ub + boff + n * 512);
#pragma unroll
        for (int m = 0; m < 4; ++m) a[m]  = *(const bf16x8*)(ua + aoff + m * 512);
        if (pf) stageA(A, brow, ktn, lds + nxt * DBUF, tid, wave);
        asm volatile("s_waitcnt lgkmcnt(0)" ::: "memory");
        __builtin_amdgcn_sched_barrier(0);
        __builtin_amdgcn_s_setprio(1);
#pragma unroll
        for (int m = 0; m < 4; ++m)
#pragma unroll
            for (int n = 0; n < 4; ++n)
                acc[m][n] = __builtin_amdgcn_mfma_f32_16x16x32_bf16(
                    a[m], b4[n], acc[m][n], 0, 0, 0);
        __builtin_amdgcn_s_setprio(0);

        // ---- phase 2: A m-half 1; stage B(t+2) ----
#pragma unroll
        for (int m = 4; m < 8; ++m) a[m] = *(const bf16x8*)(ua + aoff + m * 512);
        if (pf) stageB(B, bcol, ktn, lds + nxt * DBUF + DB_A, tid, wave);
        asm volatile("s_waitcnt lgkmcnt(0)" ::: "memory");
        __builtin_amdgcn_sched_barrier(0);
        __builtin_amdgcn_s_setprio(1);
#pragma unroll
        for (int m = 4; m < 8; ++m)
#pragma unroll
            for (int n = 0; n < 4; ++n)
                acc[m][n] = __builtin_amdgcn_mfma_f32_16x16x32_bf16(
                    a[m], b4[n], acc[m][n], 0, 0, 0);
        __builtin_amdgcn_s_setprio(0);

        cur = cur + 1; if (cur >= 3) cur -= 3;
    }

    // ---- epilogue: C/D layout col=lane&15, row=(lane>>4)*4+j; fused bias ----
#pragma unroll
    for (int n = 0; n < 4; ++n) {
        const size_t col = bcol + wc * 64 + n * 16 + lr;
        const float bs = bias[col];
#pragma unroll
        for (int m = 0; m < 8; ++m) {
            const size_t row0 = brow + (size_t)wr * 128 + m * 16 + kg * 4;
#pragma unroll
            for (int j = 0; j < 4; ++j) {
                C[(row0 + j) * N + col] = acc[m][n][j] + bs;
            }
        }
    }
}

extern "C" void kernel_launch(void* const* d_in, const int* in_sizes, int n_in,
                              void* d_out, int out_size, void* d_ws, size_t ws_size,
                              hipStream_t stream) {
    const float* x    = (const float*)d_in[0];   // [T,B,C_IN] = [M,K]
    const float* w    = (const float*)d_in[1];   // [C_OUT,C_IN] = [N,K]
    const float* bias = (const float*)d_in[2];   // [N]
    float* out = (float*)d_out;                  // [M,N]

    unsigned short* Abf = (unsigned short*)d_ws;           // 32 MiB
    unsigned short* Bbf = Abf + (size_t)M * K;             // 32 MiB

    cvt_both<<<2048, 256, 0, stream>>>(x, w, Abf, Bbf);

    gemm_2cu<<<dim3((M / BM) * (N / BN)), 256, 0, stream>>>(Abf, Bbf, bias, out);
}

// Round 10
// 151.811 us; speedup vs baseline: 1.3131x; 1.0953x over previous
//
#include <hip/hip_runtime.h>
#include <hip/hip_bf16.h>

// SparseLinear forward as DENSE bf16 MFMA GEMM:  C = A * B^T + bias (4096^3).
// R10 = R4 (best: 126.6us GEMM) minus the per-phase lgkmcnt(0)+sched_barrier(0)
// order-pins. Those forced ALL ds_reads to retire before ANY MFMA issued
// (read-wall + MFMA-wall summed). Plain-C++ LDS loads get compiler-inserted
// fine-grained lgkmcnt before each dependent MFMA, so removing the pins lets
// read-tail overlap MFMA-head. Everything else identical to R4: 256x256 tile,
// BK=64, 8 waves (2Mx4N), 4 fine phases/K-tile, counted vmcnt(4) ledger,
// zero-conflict granule-XOR swizzle, setprio, fused-bias epilogue.
// Also: single fused convert launch (x and w together).

typedef __bf16 bf16x8 __attribute__((ext_vector_type(8)));
typedef float f32x4 __attribute__((ext_vector_type(4)));

constexpr int M = 4096;   // T*B
constexpr int N = 4096;   // C_OUT
constexpr int K = 4096;   // C_IN
constexpr int BM = 256, BN = 256, BK = 64;
constexpr int NT = K / BK;          // 64 K-tiles
// One dbuf = 32768 elems (64 KiB): [A_k0][A_k1][B_k0][B_k1], each [256][32]
constexpr int DBUF = 32768;
constexpr int A_K0 = 0, A_K1 = 8192, B_K0 = 16384, B_K1 = 24576;

__device__ __forceinline__ unsigned short f2bf_rne(float f) {
    unsigned int u = __float_as_uint(f);
    u += 0x7fffu + ((u >> 16) & 1u);   // round-to-nearest-even
    return (unsigned short)(u >> 16);
}

// Fused convert: x -> Abf and w -> Bbf in one launch.
__global__ __launch_bounds__(256) void cvt_both(const float* __restrict__ x,
                                                const float* __restrict__ w,
                                                unsigned short* __restrict__ Abf,
                                                unsigned short* __restrict__ Bbf) {
    const int n8 = (M * K) / 8;
    int idx = blockIdx.x * blockDim.x + threadIdx.x;
    int stride = gridDim.x * blockDim.x;
    for (int i = idx; i < 2 * n8; i += stride) {
        const float* src;
        unsigned short* dst;
        if (i < n8) { long b = (long)i * 8;        src = x + b; dst = Abf + b; }
        else        { long b = (long)(i - n8) * 8; src = w + b; dst = Bbf + b; }
        float4 v0 = *(const float4*)(src);
        float4 v1 = *(const float4*)(src + 4);
        ushort4 r0, r1;
        r0.x = f2bf_rne(v0.x); r0.y = f2bf_rne(v0.y);
        r0.z = f2bf_rne(v0.z); r0.w = f2bf_rne(v0.w);
        r1.x = f2bf_rne(v1.x); r1.y = f2bf_rne(v1.y);
        r1.z = f2bf_rne(v1.z); r1.w = f2bf_rne(v1.w);
        *(ushort4*)(dst) = r0;
        *(ushort4*)(dst + 4) = r1;
    }
}

// Stage one k-half unit ([256 rows][32 k] = 16 KiB, 2 global_load_lds) into
// LDS (linear dest, pre-swizzled global source: cg ^= (row>>1)&3).
__device__ __forceinline__ void stage_unit(const unsigned short* __restrict__ g,
                                           size_t grow0, int kcol0,
                                           unsigned short* unitbase,
                                           int tid, int wave) {
#pragma unroll
    for (int i = 0; i < 2; ++i) {
        const int row = i * 128 + (tid >> 2);
        const int cg  = (tid & 3) ^ ((row >> 1) & 3);
        const unsigned short* src = g + (grow0 + (size_t)row) * (size_t)K
                                      + (size_t)(kcol0 + cg * 8);
        unsigned short* dst = unitbase + i * 4096 + wave * 512;
        __builtin_amdgcn_global_load_lds(
            (const __attribute__((address_space(1))) void*)src,
            (__attribute__((address_space(3))) void*)dst, 16, 0, 0);
    }
}

__global__ __launch_bounds__(512, 2) void gemm_bt_bias_np(
    const unsigned short* __restrict__ A,   // [M][K] bf16 bits
    const unsigned short* __restrict__ B,   // [N][K] bf16 bits
    const float* __restrict__ bias,         // [N]
    float* __restrict__ C)                  // [M][N] fp32
{
    __shared__ unsigned short lds[2 * DBUF];   // 128 KiB

    // XCD-aware bijective swizzle: 256 wgs, 256 % 8 == 0
    const int wg = blockIdx.x;
    const int s  = ((wg & 7) << 5) | (wg >> 3);
    const int bm = s >> 4, bn = s & 15;
    const size_t brow = (size_t)bm * BM;
    const size_t bcol = (size_t)bn * BN;

    const int tid  = threadIdx.x;
    const int wave = tid >> 6;
    const int lane = tid & 63;
    const int wr = wave >> 2;       // 0..1  (2 M-waves, 128 rows each)
    const int wc = wave & 3;        // 0..3  (4 N-waves, 64 cols each)
    const int lr = lane & 15;       // fragment row-in-16
    const int kg = lane >> 4;       // k-group 0..3

    const int a_row0 = wr * 128 + lr;
    const int b_row0 = wc * 64 + lr;
    const int aoff = a_row0 * 32 + ((kg ^ ((a_row0 >> 1) & 3)) << 3);
    const int boff = b_row0 * 32 + ((kg ^ ((b_row0 >> 1) & 3)) << 3);

    f32x4 acc[8][4];
#pragma unroll
    for (int m = 0; m < 8; ++m)
#pragma unroll
        for (int n = 0; n < 4; ++n)
            acc[m][n] = (f32x4){0.f, 0.f, 0.f, 0.f};

    // ---- prologue: stage tile 0's 4 units (8 loads) ----
    stage_unit(A, brow, 0,  lds + A_K0, tid, wave);
    stage_unit(B, bcol, 0,  lds + B_K0, tid, wave);
    stage_unit(A, brow, 32, lds + A_K1, tid, wave);
    stage_unit(B, bcol, 32, lds + B_K1, tid, wave);
    asm volatile("s_waitcnt vmcnt(4)" ::: "memory");   // A_k0, B_k0 landed
    __builtin_amdgcn_s_barrier();

    for (int t = 0; t < NT; ++t) {
        unsigned short* db = lds + (t & 1) * DBUF;        // compute buffer
        unsigned short* pb = lds + ((t & 1) ^ 1) * DBUF;  // prefetch target
        const int ktn = (t + 1) * BK;
        const bool pf = (t + 1) < NT;

        const unsigned short* pA0 = db + A_K0 + aoff;
        const unsigned short* pA1 = db + A_K1 + aoff;
        const unsigned short* pB0 = db + B_K0 + boff;
        const unsigned short* pB1 = db + B_K1 + boff;

        bf16x8 a[4], b[4];

        // ===== P1: quadrant (m-half 0, ks 0); stage A_k0(t+1) =====
#pragma unroll
        for (int n = 0; n < 4; ++n) b[n] = *(const bf16x8*)(pB0 + n * 512);
#pragma unroll
        for (int m = 0; m < 4; ++m) a[m] = *(const bf16x8*)(pA0 + m * 512);
        if (pf) stage_unit(A, brow, ktn, pb + A_K0, tid, wave);
        __builtin_amdgcn_s_barrier();
        __builtin_amdgcn_s_setprio(1);
#pragma unroll
        for (int m = 0; m < 4; ++m)
#pragma unroll
            for (int n = 0; n < 4; ++n)
                acc[m][n] = __builtin_amdgcn_mfma_f32_16x16x32_bf16(
                    a[m], b[n], acc[m][n], 0, 0, 0);
        __builtin_amdgcn_s_setprio(0);
        __builtin_amdgcn_s_barrier();

        // ===== P2: quadrant (m-half 1, ks 0), B reused; stage B_k0(t+1) =====
#pragma unroll
        for (int m = 0; m < 4; ++m) a[m] = *(const bf16x8*)(pA0 + 2048 + m * 512);
        if (pf) stage_unit(B, bcol, ktn, pb + B_K0, tid, wave);
        __builtin_amdgcn_s_barrier();
        __builtin_amdgcn_s_setprio(1);
#pragma unroll
        for (int m = 0; m < 4; ++m)
#pragma unroll
            for (int n = 0; n < 4; ++n)
                acc[4 + m][n] = __builtin_amdgcn_mfma_f32_16x16x32_bf16(
                    a[m], b[n], acc[4 + m][n], 0, 0, 0);
        __builtin_amdgcn_s_setprio(0);
        // W_b: A_k1(t), B_k1(t) (oldest 4 loads) must land before P3 reads.
        if (pf) { asm volatile("s_waitcnt vmcnt(4)" ::: "memory"); }
        else    { asm volatile("s_waitcnt vmcnt(0)" ::: "memory"); }
        __builtin_amdgcn_s_barrier();

        // ===== P3: quadrant (m-half 0, ks 1); stage A_k1(t+1) =====
#pragma unroll
        for (int n = 0; n < 4; ++n) b[n] = *(const bf16x8*)(pB1 + n * 512);
#pragma unroll
        for (int m = 0; m < 4; ++m) a[m] = *(const bf16x8*)(pA1 + m * 512);
        if (pf) stage_unit(A, brow, ktn + 32, pb + A_K1, tid, wave);
        __builtin_amdgcn_s_barrier();
        __builtin_amdgcn_s_setprio(1);
#pragma unroll
        for (int m = 0; m < 4; ++m)
#pragma unroll
            for (int n = 0; n < 4; ++n)
                acc[m][n] = __builtin_amdgcn_mfma_f32_16x16x32_bf16(
                    a[m], b[n], acc[m][n], 0, 0, 0);
        __builtin_amdgcn_s_setprio(0);
        __builtin_amdgcn_s_barrier();

        // ===== P4: quadrant (m-half 1, ks 1), B reused; stage B_k1(t+1) =====
#pragma unroll
        for (int m = 0; m < 4; ++m) a[m] = *(const bf16x8*)(pA1 + 2048 + m * 512);
        if (pf) stage_unit(B, bcol, ktn + 32, pb + B_K1, tid, wave);
        __builtin_amdgcn_s_barrier();
        __builtin_amdgcn_s_setprio(1);
#pragma unroll
        for (int m = 0; m < 4; ++m)
#pragma unroll
            for (int n = 0; n < 4; ++n)
                acc[4 + m][n] = __builtin_amdgcn_mfma_f32_16x16x32_bf16(
                    a[m], b[n], acc[4 + m][n], 0, 0, 0);
        __builtin_amdgcn_s_setprio(0);
        // W_a: A_k0(t+1), B_k0(t+1) (oldest 4) must land before P1(t+1) reads.
        if (pf) {
            asm volatile("s_waitcnt vmcnt(4)" ::: "memory");
            __builtin_amdgcn_s_barrier();
        }
    }

    // ---- epilogue: C/D layout col=lane&15, row=(lane>>4)*4+j; fused bias ----
#pragma unroll
    for (int n = 0; n < 4; ++n) {
        const size_t col = bcol + wc * 64 + n * 16 + lr;
        const float bs = bias[col];
#pragma unroll
        for (int m = 0; m < 8; ++m) {
            const size_t row0 = brow + (size_t)wr * 128 + m * 16 + kg * 4;
#pragma unroll
            for (int j = 0; j < 4; ++j) {
                C[(row0 + j) * N + col] = acc[m][n][j] + bs;
            }
        }
    }
}

extern "C" void kernel_launch(void* const* d_in, const int* in_sizes, int n_in,
                              void* d_out, int out_size, void* d_ws, size_t ws_size,
                              hipStream_t stream) {
    const float* x    = (const float*)d_in[0];   // [T,B,C_IN] = [M,K]
    const float* w    = (const float*)d_in[1];   // [C_OUT,C_IN] = [N,K]
    const float* bias = (const float*)d_in[2];   // [N]
    float* out = (float*)d_out;                  // [M,N]

    unsigned short* Abf = (unsigned short*)d_ws;           // 32 MiB
    unsigned short* Bbf = Abf + (size_t)M * K;             // 32 MiB

    cvt_both<<<2048, 256, 0, stream>>>(x, w, Abf, Bbf);

    gemm_bt_bias_np<<<dim3((M / BM) * (N / BN)), 512, 0, stream>>>(Abf, Bbf, bias, out);
}